// Round 9
// baseline (296.614 us; speedup 1.0000x reference)
//
#include <hip/hip_runtime.h>
#include <hip/hip_bf16.h>
#include <math.h>

#define H_DIM 1024
#define SEQ   2048
#define BATCH 2
#define NHEAD 16
#define DKV   64
#define ROWS  (BATCH*SEQ)   // 4096

typedef __attribute__((ext_vector_type(8))) short short8;
typedef __attribute__((ext_vector_type(4))) float f32x4;

static __device__ __forceinline__ unsigned short f32_bf16(float f) {
    unsigned int u = __builtin_bit_cast(unsigned int, f);
    u += 0x7FFF + ((u >> 16) & 1);          // RNE
    return (unsigned short)(u >> 16);
}

// A&S 7.1.26 rational-poly erf, |err| < 1.5e-7
static __device__ __forceinline__ float fast_erf(float x) {
    float ax = fabsf(x);
    float t = 1.0f / fmaf(0.3275911f, ax, 1.0f);
    float p = t * fmaf(t, fmaf(t, fmaf(t, fmaf(t, 1.061405429f, -1.453152027f),
                                       1.421413741f), -0.284496736f), 0.254829592f);
    float y = fmaf(-p, __expf(-ax * ax), 1.0f);
    return copysignf(y, x);
}

static __device__ __forceinline__ void gload16(const unsigned short* g, unsigned short* l) {
    __builtin_amdgcn_global_load_lds(
        (const __attribute__((address_space(1))) void*)g,
        (__attribute__((address_space(3))) void*)l,
        16, 0, 0);
}

#define BARRIER  asm volatile("s_barrier" ::: "memory")
#define SYNC_V4  asm volatile("s_waitcnt vmcnt(4)\n\ts_barrier" ::: "memory")
#define SYNC_V0  asm volatile("s_waitcnt vmcnt(0)\n\ts_barrier" ::: "memory")

// ---------------- fp32 [K][N] -> bf16 [N][K] transpose ----------------
__global__ __launch_bounds__(256) void transpose_bf16(const float* __restrict__ in,
                                                      unsigned short* __restrict__ out,
                                                      int K, int N) {
    __shared__ float tile[32][33];
    int n0 = blockIdx.x * 32, k0 = blockIdx.y * 32;
    int tx = threadIdx.x & 31, ty = threadIdx.x >> 5;   // 32 x 8
    #pragma unroll
    for (int i = 0; i < 4; ++i)
        tile[ty + i * 8][tx] = in[(size_t)(k0 + ty + i * 8) * N + n0 + tx];
    __syncthreads();
    #pragma unroll
    for (int i = 0; i < 4; ++i)
        out[(size_t)(n0 + ty + i * 8) * K + k0 + tx] = f32_bf16(tile[tx][ty + i * 8]);
}

// ---------------- LayerNorm (fp32 in -> bf16 out) ----------------
__global__ __launch_bounds__(256) void ln_bf16(const float* __restrict__ x,
                                               const float* __restrict__ w,
                                               const float* __restrict__ bb,
                                               unsigned short* __restrict__ out) {
    int row = blockIdx.x;
    int tid = threadIdx.x;
    float4 v = ((const float4*)(x + (size_t)row * H_DIM))[tid];
    float s  = v.x + v.y + v.z + v.w;
    float s2 = v.x*v.x + v.y*v.y + v.z*v.z + v.w*v.w;
    #pragma unroll
    for (int off = 1; off < 64; off <<= 1) {
        s  += __shfl_xor(s,  off, 64);
        s2 += __shfl_xor(s2, off, 64);
    }
    __shared__ float red[8];
    int wv = tid >> 6;
    if ((tid & 63) == 0) { red[wv] = s; red[4 + wv] = s2; }
    __syncthreads();
    s  = red[0] + red[1] + red[2] + red[3];
    s2 = red[4] + red[5] + red[6] + red[7];
    float mu = s * (1.0f / H_DIM);
    float rs = rsqrtf(s2 * (1.0f / H_DIM) - mu * mu + 1e-5f);
    float4 wv4 = ((const float4*)w)[tid];
    float4 bv4 = ((const float4*)bb)[tid];
    ushort4 o;
    o.x = f32_bf16((v.x - mu) * rs * wv4.x + bv4.x);
    o.y = f32_bf16((v.y - mu) * rs * wv4.y + bv4.y);
    o.z = f32_bf16((v.z - mu) * rs * wv4.z + bv4.z);
    o.w = f32_bf16((v.w - mu) * rs * wv4.w + bv4.w);
    ((ushort4*)(out + (size_t)row * H_DIM))[tid] = o;
}

// ======== epilogue helper ========
template<int EPI>
static __device__ __forceinline__ void epi_store(f32x4 a, int row0, int col, int N,
                                                 const float* __restrict__ bias,
                                                 const float* __restrict__ resid,
                                                 float* __restrict__ outF,
                                                 unsigned short* __restrict__ outH,
                                                 unsigned short* __restrict__ outH2) {
    float bv = bias[col];
    if (EPI == 4 && col >= 2048) {
        int bb = row0 >> 11, ss = row0 & 2047;
        int hd = col - 2048;
        ushort4 u;
        u.x = f32_bf16(a[0] + bv);
        u.y = f32_bf16(a[1] + bv);
        u.z = f32_bf16(a[2] + bv);
        u.w = f32_bf16(a[3] + bv);
        *(ushort4*)&outH2[((size_t)bb * 1024 + hd) * SEQ + ss] = u;
    } else {
        #pragma unroll
        for (int j = 0; j < 4; ++j) {
            int row = row0 + j;
            size_t idx = (size_t)row * N + col;
            float c = a[j] + bv;
            if (EPI == 0) {
                outF[idx] = c;
            } else if (EPI == 1) {
                outF[idx] = resid[idx] + c;
            } else if (EPI == 2) {
                float g = 0.5f * c * (1.0f + fast_erf(c * 0.70710678118f));
                outH[idx] = f32_bf16(g);
            } else if (EPI == 3) {
                outH[idx] = f32_bf16(c);
            } else {
                outH[(size_t)row * 2048 + col] = f32_bf16(c);   // Q|K packed
            }
        }
    }
}

// ---------------- bf16 MFMA GEMM, 128x128 tile, BK=64, single-buffer (round-7 proven) ----------------
template<int EPI>
__global__ __launch_bounds__(256) void gemm128(const unsigned short* __restrict__ A,
                                               const unsigned short* __restrict__ Bt,
                                               const float* __restrict__ bias,
                                               const float* __restrict__ resid,
                                               float* __restrict__ outF,
                                               unsigned short* __restrict__ outH,
                                               unsigned short* __restrict__ outH2,
                                               int N, int K) {
    __shared__ __attribute__((aligned(16))) unsigned short As[128][64];
    __shared__ __attribute__((aligned(16))) unsigned short Bs[128][64];
    int tid = threadIdx.x;
    int w = tid >> 6, l = tid & 63;
    int l15 = l & 15, lg = l >> 4;
    int wm = w & 1, wn = w >> 1;
    int m0 = blockIdx.y * 128, n0 = blockIdx.x * 128;

    f32x4 acc[4][4] = {};

    const unsigned short* aptr[4];
    const unsigned short* bptr[4];
    unsigned short* lA[4];
    unsigned short* lB[4];
    #pragma unroll
    for (int j = 0; j < 4; ++j) {
        int slot = (w * 4 + j) * 64 + l;          // 0..1023
        int row = slot >> 3;
        int lchunk = (slot & 7) ^ (row & 7);      // pre-swizzled source chunk
        aptr[j] = A  + (size_t)(m0 + row) * K + lchunk * 8;
        bptr[j] = Bt + (size_t)(n0 + row) * K + lchunk * 8;
        lA[j] = &As[0][0] + (w * 4 + j) * 512;
        lB[j] = &Bs[0][0] + (w * 4 + j) * 512;
    }
    int swz[2];
    swz[0] = ((0 + lg) ^ (l15 & 7)) * 8;
    swz[1] = ((4 + lg) ^ (l15 & 7)) * 8;
    const unsigned short* pA = &As[wm * 64 + l15][0];
    const unsigned short* pB = &Bs[wn * 64 + l15][0];

    for (int k0 = 0; k0 < K; k0 += 64) {
        __syncthreads();
        #pragma unroll
        for (int j = 0; j < 4; ++j) gload16(aptr[j] + k0, lA[j]);
        #pragma unroll
        for (int j = 0; j < 4; ++j) gload16(bptr[j] + k0, lB[j]);
        __syncthreads();

        #pragma unroll
        for (int ks = 0; ks < 2; ++ks) {
            short8 af[4], bf[4];
            #pragma unroll
            for (int mi = 0; mi < 4; ++mi)
                af[mi] = *(const short8*)(pA + mi * 16 * 64 + swz[ks]);
            #pragma unroll
            for (int ni = 0; ni < 4; ++ni)
                bf[ni] = *(const short8*)(pB + ni * 16 * 64 + swz[ks]);
            #pragma unroll
            for (int mi = 0; mi < 4; ++mi)
                #pragma unroll
                for (int ni = 0; ni < 4; ++ni)
                    acc[mi][ni] = __builtin_amdgcn_mfma_f32_16x16x32_bf16(af[mi], bf[ni], acc[mi][ni], 0, 0, 0);
        }
    }

    #pragma unroll
    for (int mi = 0; mi < 4; ++mi)
        #pragma unroll
        for (int ni = 0; ni < 4; ++ni)
            epi_store<EPI>(acc[mi][ni], m0 + wm * 64 + mi * 16 + lg * 4,
                           n0 + wn * 64 + ni * 16 + l15, N, bias, resid, outF, outH, outH2);
}

// ---------------- bf16 MFMA GEMM, 256x256, BK=64, 4-phase counted-vmcnt pipeline ----------------
// LDS: k-split half-tiles As[dbuf][khalf][256 rows][32 cols] (16KB regions, linear-stageable).
// Swizzle: physical chunk = logical ^ ((row>>1)&3) within each 64B row (2-way = free).
// Per K-tile: 4 phases; stage order A-kh0, B-kh0, A-kh1, B-kh1 of tile t+1 (into dbuf^1);
// s_waitcnt vmcnt(4) at phase-1/phase-3 ends (the 4 outstanding = this tile's fresh stages,
// everything older proven landed). Loads never drain to 0 in steady state (T3+T4).
template<int EPI>
__global__ __launch_bounds__(512) void gemm256p(const unsigned short* __restrict__ A,
                                                const unsigned short* __restrict__ Bt,
                                                const float* __restrict__ bias,
                                                const float* __restrict__ resid,
                                                float* __restrict__ outF,
                                                unsigned short* __restrict__ outH,
                                                unsigned short* __restrict__ outH2,
                                                int N, int K) {
    __shared__ __attribute__((aligned(16))) unsigned short As[2][2][256 * 32];  // 64 KB
    __shared__ __attribute__((aligned(16))) unsigned short Bs[2][2][256 * 32];  // 64 KB
    int tid = threadIdx.x;
    int w = tid >> 6, l = tid & 63;
    int l15 = l & 15, lg = l >> 4;
    int wm = w >> 2, wn = w & 3;                  // 2 (M) x 4 (N)
    int m0 = blockIdx.y * 256, n0 = blockIdx.x * 256;

    f32x4 acc[8][4] = {};

    // staging: half-tile = 256 rows x 32 cols = 16KB = 512 thr x 2 x 16B
    int sr0 = tid >> 2,          sr1 = (512 + tid) >> 2;
    int sc0 = ((tid & 3) ^ ((sr0 >> 1) & 3)) * 8;
    int sc1 = ((tid & 3) ^ ((sr1 >> 1) & 3)) * 8;
    size_t saA0 = (size_t)(m0 + sr0) * K + sc0, saA1 = (size_t)(m0 + sr1) * K + sc1;
    size_t saB0 = (size_t)(n0 + sr0) * K + sc0, saB1 = (size_t)(n0 + sr1) * K + sc1;
    int ld0 = tid * 8, ld1 = (512 + tid) * 8;     // element offsets in 16KB region

#define STAGE_A(dn, h, kt) { gload16(A  + saA0 + (kt) * 64 + (h) * 32, &As[dn][h][0] + ld0); \
                             gload16(A  + saA1 + (kt) * 64 + (h) * 32, &As[dn][h][0] + ld1); }
#define STAGE_B(dn, h, kt) { gload16(Bt + saB0 + (kt) * 64 + (h) * 32, &Bs[dn][h][0] + ld0); \
                             gload16(Bt + saB1 + (kt) * 64 + (h) * 32, &Bs[dn][h][0] + ld1); }

    // read offsets: row r -> r*32 + (lg ^ ((r>>1)&3))*8 ; (r>>1)&3 == (l15>>1)&3 here
    int pcho = ((lg ^ ((l15 >> 1) & 3)) << 3);
    int offA[8], offB[4];
    #pragma unroll
    for (int mi = 0; mi < 8; ++mi) offA[mi] = (wm * 128 + mi * 16 + l15) * 32 + pcho;
    #pragma unroll
    for (int ni = 0; ni < 4; ++ni) offB[ni] = (wn * 64 + ni * 16 + l15) * 32 + pcho;

#define MFMA_Q(base) { __builtin_amdgcn_s_setprio(1); \
    _Pragma("unroll") for (int mi = 0; mi < 4; ++mi) \
        _Pragma("unroll") for (int ni = 0; ni < 4; ++ni) \
            acc[(base) + mi][ni] = __builtin_amdgcn_mfma_f32_16x16x32_bf16(af[mi], bf[ni], acc[(base) + mi][ni], 0, 0, 0); \
    __builtin_amdgcn_s_setprio(0); }

    int nt = K >> 6;
    // prologue: tile 0 (dbuf 0), all four halves; kh0 must land before phase 0
    STAGE_A(0, 0, 0); STAGE_B(0, 0, 0);
    STAGE_A(0, 1, 0); STAGE_B(0, 1, 0);
    SYNC_V4;                                       // kh0 A+B landed (kh1's 4 still flying)

    short8 af[4], bf[4];
    for (int t = 0; t < nt - 1; ++t) {
        int d = t & 1, dn = d ^ 1;
        // ---- phase 0: ks=0, mi 0-3 ----
        #pragma unroll
        for (int ni = 0; ni < 4; ++ni) bf[ni] = *(const short8*)&Bs[d][0][offB[ni]];
        #pragma unroll
        for (int mi = 0; mi < 4; ++mi) af[mi] = *(const short8*)&As[d][0][offA[mi]];
        STAGE_A(dn, 0, t + 1);
        BARRIER;
        MFMA_Q(0);
        // ---- phase 1: ks=0, mi 4-7 ----
        #pragma unroll
        for (int mi = 0; mi < 4; ++mi) af[mi] = *(const short8*)&As[d][0][offA[4 + mi]];
        STAGE_B(dn, 0, t + 1);
        BARRIER;
        MFMA_Q(4);
        SYNC_V4;                                   // cur kh1 landed; next kh0 (4) in flight
        // ---- phase 2: ks=1, mi 0-3 ----
        #pragma unroll
        for (int ni = 0; ni < 4; ++ni) bf[ni] = *(const short8*)&Bs[d][1][offB[ni]];
        #pragma unroll
        for (int mi = 0; mi < 4; ++mi) af[mi] = *(const short8*)&As[d][1][offA[mi]];
        STAGE_A(dn, 1, t + 1);
        BARRIER;
        MFMA_Q(0);
        // ---- phase 3: ks=1, mi 4-7 ----
        #pragma unroll
        for (int mi = 0; mi < 4; ++mi) af[mi] = *(const short8*)&As[d][1][offA[4 + mi]];
        STAGE_B(dn, 1, t + 1);
        BARRIER;
        MFMA_Q(4);
        SYNC_V4;                                   // next kh0 landed; next kh1 (4) in flight
    }
    {   // ---- last tile (no staging; drain kh1 before reading it) ----
        int d = (nt - 1) & 1;
        #pragma unroll
        for (int ni = 0; ni < 4; ++ni) bf[ni] = *(const short8*)&Bs[d][0][offB[ni]];
        #pragma unroll
        for (int mi = 0; mi < 4; ++mi) af[mi] = *(const short8*)&As[d][0][offA[mi]];
        BARRIER;
        MFMA_Q(0);
        #pragma unroll
        for (int mi = 0; mi < 4; ++mi) af[mi] = *(const short8*)&As[d][0][offA[4 + mi]];
        BARRIER;
        MFMA_Q(4);
        SYNC_V0;                                   // kh1 (staged last tile) fully landed
        #pragma unroll
        for (int ni = 0; ni < 4; ++ni) bf[ni] = *(const short8*)&Bs[d][1][offB[ni]];
        #pragma unroll
        for (int mi = 0; mi < 4; ++mi) af[mi] = *(const short8*)&As[d][1][offA[mi]];
        MFMA_Q(0);
        #pragma unroll
        for (int mi = 0; mi < 4; ++mi) af[mi] = *(const short8*)&As[d][1][offA[4 + mi]];
        MFMA_Q(4);
    }
#undef STAGE_A
#undef STAGE_B
#undef MFMA_Q

    #pragma unroll
    for (int mi = 0; mi < 8; ++mi)
        #pragma unroll
        for (int ni = 0; ni < 4; ++ni)
            epi_store<EPI>(acc[mi][ni], m0 + wm * 128 + mi * 16 + lg * 4,
                           n0 + wn * 64 + ni * 16 + l15, N, bias, resid, outF, outH, outH2);
}

// ---------------- causal flash attention, swapped-operand softmax ----------------
__global__ __launch_bounds__(256) void attn_mfma(const unsigned short* __restrict__ qk,
                                                 const unsigned short* __restrict__ vT,
                                                 unsigned short* __restrict__ out) {
    int bid = blockIdx.x;
    int swz = (bid & 7) * 128 + (bid >> 3);
    int b  = swz >> 9;
    int h  = (swz >> 5) & 15;
    int qt = 31 - (swz & 31);
    int tid = threadIdx.x;
    int w = tid >> 6, l = tid & 63;
    int l15 = l & 15, lg = l >> 4;

    __shared__ __attribute__((aligned(16))) unsigned short Ks[64][72];
    __shared__ __attribute__((aligned(16))) unsigned short Vt[64][72];
    __shared__ __attribute__((aligned(16))) unsigned short Ps[4][16][72];

    int qrow = qt * 64 + w * 16 + l15;
    short8 qf[2];
    {
        const unsigned short* qp = qk + (size_t)(b * SEQ + qrow) * 2048 + h * DKV + lg * 8;
        qf[0] = *(const short8*)qp;
        qf[1] = *(const short8*)(qp + 32);
    }

    int srow = l >> 2;
    int scol = (l & 3) * 16;
    int krow = w * 16 + srow;
    const unsigned short* kbase = qk + (size_t)(b * SEQ + krow) * 2048 + 1024 + h * DKV + scol;
    const unsigned short* vbase = vT + ((size_t)(b * NHEAD + h) * DKV + krow) * SEQ + scol;

    short8 kr0 = *(const short8*)kbase;
    short8 kr1 = *(const short8*)(kbase + 8);
    short8 vr0 = *(const short8*)vbase;
    short8 vr1 = *(const short8*)(vbase + 8);

    float m = -1e30f, lsum = 0.0f;
    f32x4 oacc[4] = {};

    for (int kt = 0; kt <= qt; ++kt) {
        __syncthreads();
        *(short8*)&Ks[krow][scol]     = kr0;
        *(short8*)&Ks[krow][scol + 8] = kr1;
        *(short8*)&Vt[krow][scol]     = vr0;
        *(short8*)&Vt[krow][scol + 8] = vr1;
        __syncthreads();
        if (kt < qt) {
            const unsigned short* kp = kbase + (size_t)(kt + 1) * 64 * 2048;
            const unsigned short* vp = vbase + (kt + 1) * 64;
            kr0 = *(const short8*)kp;
            kr1 = *(const short8*)(kp + 8);
            vr0 = *(const short8*)vp;
            vr1 = *(const short8*)(vp + 8);
        }

        f32x4 sc[4] = {};
        __builtin_amdgcn_s_setprio(1);
        #pragma unroll
        for (int dstep = 0; dstep < 2; ++dstep) {
            #pragma unroll
            for (int st = 0; st < 4; ++st) {
                short8 kf = *(const short8*)&Ks[st * 16 + l15][dstep * 32 + lg * 8];
                sc[st] = __builtin_amdgcn_mfma_f32_16x16x32_bf16(kf, qf[dstep], sc[st], 0, 0, 0);
            }
        }
        __builtin_amdgcn_s_setprio(0);

        bool diag = (kt == qt);
        int klim = w * 16 + l15;
        float pv[4][4];
        float pmax = -1e30f;
        #pragma unroll
        for (int st = 0; st < 4; ++st) {
            #pragma unroll
            for (int j = 0; j < 4; ++j) {
                float s = sc[st][j] * 0.125f;
                if (diag && (st * 16 + lg * 4 + j > klim)) s = -1e30f;
                pv[st][j] = s;
                pmax = fmaxf(pmax, s);
            }
        }
        pmax = fmaxf(pmax, __shfl_xor(pmax, 16, 64));
        pmax = fmaxf(pmax, __shfl_xor(pmax, 32, 64));

        if (!__all(pmax - m <= 8.0f)) {
            float mn = fmaxf(m, pmax);
            float scl = __expf(m - mn);
            lsum *= scl;
            #pragma unroll
            for (int d = 0; d < 4; ++d)
                #pragma unroll
                for (int j = 0; j < 4; ++j)
                    oacc[d][j] *= scl;
            m = mn;
        }

        float ps = 0.0f;
        #pragma unroll
        for (int st = 0; st < 4; ++st) {
            ushort4 u;
            #pragma unroll
            for (int j = 0; j < 4; ++j) {
                float p = __expf(pv[st][j] - m);
                ps += p;
                ((unsigned short*)&u)[j] = f32_bf16(p);
            }
            *(ushort4*)&Ps[w][l15][st * 16 + lg * 4] = u;
        }
        ps += __shfl_xor(ps, 16, 64);
        ps += __shfl_xor(ps, 32, 64);
        lsum += ps;

        __builtin_amdgcn_s_setprio(1);
        #pragma unroll
        for (int ks = 0; ks < 2; ++ks) {
            short8 pf = *(const short8*)&Ps[w][l15][ks * 32 + lg * 8];
            #pragma unroll
            for (int d = 0; d < 4; ++d) {
                short8 vf = *(const short8*)&Vt[d * 16 + l15][ks * 32 + lg * 8];
                oacc[d] = __builtin_amdgcn_mfma_f32_16x16x32_bf16(vf, pf, oacc[d], 0, 0, 0);
            }
        }
        __builtin_amdgcn_s_setprio(0);
    }

    float inv = 1.0f / lsum;
    size_t ob = (size_t)(b * SEQ + qrow) * H_DIM + h * DKV;
    #pragma unroll
    for (int d = 0; d < 4; ++d) {
        ushort4 u;
        #pragma unroll
        for (int j = 0; j < 4; ++j)
            ((unsigned short*)&u)[j] = f32_bf16(oacc[d][j] * inv);
        *(ushort4*)&out[ob + d * 16 + lg * 4] = u;
    }
}

// ---------------- launch ----------------
extern "C" void kernel_launch(void* const* d_in, const int* in_sizes, int n_in,
                              void* d_out, int out_size, void* d_ws, size_t ws_size,
                              hipStream_t stream) {
    const float* x     = (const float*)d_in[0];
    const float* ln1w  = (const float*)d_in[1];
    const float* ln1b  = (const float*)d_in[2];
    const float* Wqkv  = (const float*)d_in[3];
    const float* bqkv  = (const float*)d_in[4];
    const float* Wo    = (const float*)d_in[5];
    const float* bo    = (const float*)d_in[6];
    const float* ln2w  = (const float*)d_in[7];
    const float* ln2b  = (const float*)d_in[8];
    const float* Wfc   = (const float*)d_in[9];
    const float* bfc   = (const float*)d_in[10];
    const float* Wproj = (const float*)d_in[11];
    const float* bproj = (const float*)d_in[12];
    float* out = (float*)d_out;

    char* ws = (char*)d_ws;
    size_t off = 0;
    auto take = [&](size_t bytes) {
        void* p = ws + off;
        off += (bytes + 255) & ~(size_t)255;
        return p;
    };

    unsigned short* WqT  = (unsigned short*)take((size_t)3072 * 1024 * 2);
    unsigned short* WoT  = (unsigned short*)take((size_t)1024 * 1024 * 2);
    unsigned short* WfcT = (unsigned short*)take((size_t)4096 * 1024 * 2);
    unsigned short* WpT  = (unsigned short*)take((size_t)1024 * 4096 * 2);
    unsigned short* xn1   = (unsigned short*)take((size_t)ROWS * 1024 * 2);
    unsigned short* qk_h  = (unsigned short*)take((size_t)ROWS * 2048 * 2);
    unsigned short* vT    = (unsigned short*)take((size_t)ROWS * 1024 * 2);
    unsigned short* attn  = (unsigned short*)take((size_t)ROWS * 1024 * 2);
    float*          x1    = (float*)take((size_t)ROWS * 1024 * 4);
    unsigned short* xn2   = (unsigned short*)take((size_t)ROWS * 1024 * 2);
    unsigned short* hbuf  = (unsigned short*)take((size_t)ROWS * 4096 * 2);

    // weight transposes fp32[K][N] -> bf16[N][K]
    transpose_bf16<<<dim3(3072 / 32, 1024 / 32), 256, 0, stream>>>(Wqkv,  WqT,  1024, 3072);
    transpose_bf16<<<dim3(1024 / 32, 1024 / 32), 256, 0, stream>>>(Wo,    WoT,  1024, 1024);
    transpose_bf16<<<dim3(4096 / 32, 1024 / 32), 256, 0, stream>>>(Wfc,   WfcT, 1024, 4096);
    transpose_bf16<<<dim3(1024 / 32, 4096 / 32), 256, 0, stream>>>(Wproj, WpT,  4096, 1024);

    // LN1 -> xn1 (bf16)
    ln_bf16<<<ROWS, 256, 0, stream>>>(x, ln1w, ln1b, xn1);

    // QKV: Q|K -> qk_h packed, V -> vT transposed   (256^2 pipelined)
    gemm256p<4><<<dim3(3072 / 256, ROWS / 256), 512, 0, stream>>>(xn1, WqT, bqkv, nullptr, nullptr, qk_h, vT, 3072, 1024);

    // causal attention -> attn (bf16)
    attn_mfma<<<1024, 256, 0, stream>>>(qk_h, vT, attn);

    // x1 = x + attn @ Wo + bo
    gemm128<1><<<dim3(1024 / 128, ROWS / 128), 256, 0, stream>>>(attn, WoT, bo, x, x1, nullptr, nullptr, 1024, 1024);

    // LN2 -> xn2 (bf16)
    ln_bf16<<<ROWS, 256, 0, stream>>>(x1, ln2w, ln2b, xn2);

    // h = gelu(xn2 @ Wfc + bfc) (bf16)   (256^2 pipelined)
    gemm256p<2><<<dim3(4096 / 256, ROWS / 256), 512, 0, stream>>>(xn2, WfcT, bfc, nullptr, nullptr, hbuf, nullptr, 4096, 1024);

    // out = x1 + h @ Wproj + bproj
    gemm128<1><<<dim3(1024 / 128, ROWS / 128), 256, 0, stream>>>(hbuf, WpT, bproj, x1, out, nullptr, nullptr, 1024, 4096);
}

// Round 10
// 281.236 us; speedup vs baseline: 1.0547x; 1.0547x over previous
//
#include <hip/hip_runtime.h>
#include <hip/hip_bf16.h>
#include <math.h>

#define H_DIM 1024
#define SEQ   2048
#define BATCH 2
#define NHEAD 16
#define DKV   64
#define ROWS  (BATCH*SEQ)   // 4096

typedef __attribute__((ext_vector_type(8))) short short8;
typedef __attribute__((ext_vector_type(4))) float f32x4;

static __device__ __forceinline__ unsigned short f32_bf16(float f) {
    unsigned int u = __builtin_bit_cast(unsigned int, f);
    u += 0x7FFF + ((u >> 16) & 1);          // RNE
    return (unsigned short)(u >> 16);
}

// A&S 7.1.26 rational-poly erf, |err| < 1.5e-7
static __device__ __forceinline__ float fast_erf(float x) {
    float ax = fabsf(x);
    float t = 1.0f / fmaf(0.3275911f, ax, 1.0f);
    float p = t * fmaf(t, fmaf(t, fmaf(t, fmaf(t, 1.061405429f, -1.453152027f),
                                       1.421413741f), -0.284496736f), 0.254829592f);
    float y = fmaf(-p, __expf(-ax * ax), 1.0f);
    return copysignf(y, x);
}

static __device__ __forceinline__ void gload16(const unsigned short* g, unsigned short* l) {
    __builtin_amdgcn_global_load_lds(
        (const __attribute__((address_space(1))) void*)g,
        (__attribute__((address_space(3))) void*)l,
        16, 0, 0);
}

// ---------------- fp32 [K][N] -> bf16 [N][K] transpose ----------------
__global__ __launch_bounds__(256) void transpose_bf16(const float* __restrict__ in,
                                                      unsigned short* __restrict__ out,
                                                      int K, int N) {
    __shared__ float tile[32][33];
    int n0 = blockIdx.x * 32, k0 = blockIdx.y * 32;
    int tx = threadIdx.x & 31, ty = threadIdx.x >> 5;   // 32 x 8
    #pragma unroll
    for (int i = 0; i < 4; ++i)
        tile[ty + i * 8][tx] = in[(size_t)(k0 + ty + i * 8) * N + n0 + tx];
    __syncthreads();
    #pragma unroll
    for (int i = 0; i < 4; ++i)
        out[(size_t)(n0 + ty + i * 8) * K + k0 + tx] = f32_bf16(tile[tx][ty + i * 8]);
}

// ---------------- LayerNorm (fp32 in -> bf16 out) ----------------
__global__ __launch_bounds__(256) void ln_bf16(const float* __restrict__ x,
                                               const float* __restrict__ w,
                                               const float* __restrict__ bb,
                                               unsigned short* __restrict__ out) {
    int row = blockIdx.x;
    int tid = threadIdx.x;
    float4 v = ((const float4*)(x + (size_t)row * H_DIM))[tid];
    float s  = v.x + v.y + v.z + v.w;
    float s2 = v.x*v.x + v.y*v.y + v.z*v.z + v.w*v.w;
    #pragma unroll
    for (int off = 1; off < 64; off <<= 1) {
        s  += __shfl_xor(s,  off, 64);
        s2 += __shfl_xor(s2, off, 64);
    }
    __shared__ float red[8];
    int wv = tid >> 6;
    if ((tid & 63) == 0) { red[wv] = s; red[4 + wv] = s2; }
    __syncthreads();
    s  = red[0] + red[1] + red[2] + red[3];
    s2 = red[4] + red[5] + red[6] + red[7];
    float mu = s * (1.0f / H_DIM);
    float rs = rsqrtf(s2 * (1.0f / H_DIM) - mu * mu + 1e-5f);
    float4 wv4 = ((const float4*)w)[tid];
    float4 bv4 = ((const float4*)bb)[tid];
    ushort4 o;
    o.x = f32_bf16((v.x - mu) * rs * wv4.x + bv4.x);
    o.y = f32_bf16((v.y - mu) * rs * wv4.y + bv4.y);
    o.z = f32_bf16((v.z - mu) * rs * wv4.z + bv4.z);
    o.w = f32_bf16((v.w - mu) * rs * wv4.w + bv4.w);
    ((ushort4*)(out + (size_t)row * H_DIM))[tid] = o;
}

// ======== epilogue helper ========
template<int EPI>
static __device__ __forceinline__ void epi_store(f32x4 a, int row0, int col, int N,
                                                 const float* __restrict__ bias,
                                                 const float* __restrict__ resid,
                                                 float* __restrict__ outF,
                                                 unsigned short* __restrict__ outH,
                                                 unsigned short* __restrict__ outH2) {
    float bv = bias[col];
    if (EPI == 4 && col >= 2048) {
        int bb = row0 >> 11, ss = row0 & 2047;
        int hd = col - 2048;
        ushort4 u;
        u.x = f32_bf16(a[0] + bv);
        u.y = f32_bf16(a[1] + bv);
        u.z = f32_bf16(a[2] + bv);
        u.w = f32_bf16(a[3] + bv);
        *(ushort4*)&outH2[((size_t)bb * 1024 + hd) * SEQ + ss] = u;
    } else {
        #pragma unroll
        for (int j = 0; j < 4; ++j) {
            int row = row0 + j;
            size_t idx = (size_t)row * N + col;
            float c = a[j] + bv;
            if (EPI == 0) {
                outF[idx] = c;
            } else if (EPI == 1) {
                outF[idx] = resid[idx] + c;
            } else if (EPI == 2) {
                float g = 0.5f * c * (1.0f + fast_erf(c * 0.70710678118f));
                outH[idx] = f32_bf16(g);
            } else if (EPI == 3) {
                outH[idx] = f32_bf16(c);
            } else {
                outH[(size_t)row * 2048 + col] = f32_bf16(c);   // Q|K packed
            }
        }
    }
}

// ---------------- bf16 MFMA GEMM, 128x128 tile, BK=64, single-buffer,
//                  flat grid + XCD-chunked swizzle (T1) ----------------
// gx = N-tile count; within an XCD chunk block ids are n-fastest, so the
// ~gridDim/8 consecutive blocks on one XCD share a few A row-panels (L2-fit).
template<int EPI>
__global__ __launch_bounds__(256) void gemm128(const unsigned short* __restrict__ A,
                                               const unsigned short* __restrict__ Bt,
                                               const float* __restrict__ bias,
                                               const float* __restrict__ resid,
                                               float* __restrict__ outF,
                                               unsigned short* __restrict__ outH,
                                               unsigned short* __restrict__ outH2,
                                               int gx, int N, int K) {
    __shared__ __attribute__((aligned(16))) unsigned short As[128][64];
    __shared__ __attribute__((aligned(16))) unsigned short Bs[128][64];
    int tid = threadIdx.x;
    int w = tid >> 6, l = tid & 63;
    int l15 = l & 15, lg = l >> 4;
    int wm = w & 1, wn = w >> 1;

    // bijective XCD-chunk swizzle (gridDim.x % 8 == 0 for all our launches)
    int qq = gridDim.x >> 3;
    int wg = (blockIdx.x & 7) * qq + (blockIdx.x >> 3);
    int bm = wg / gx, bn = wg - bm * gx;
    int m0 = bm * 128, n0 = bn * 128;

    f32x4 acc[4][4] = {};

    const unsigned short* aptr[4];
    const unsigned short* bptr[4];
    unsigned short* lA[4];
    unsigned short* lB[4];
    #pragma unroll
    for (int j = 0; j < 4; ++j) {
        int slot = (w * 4 + j) * 64 + l;          // 0..1023
        int row = slot >> 3;
        int lchunk = (slot & 7) ^ (row & 7);      // pre-swizzled source chunk
        aptr[j] = A  + (size_t)(m0 + row) * K + lchunk * 8;
        bptr[j] = Bt + (size_t)(n0 + row) * K + lchunk * 8;
        lA[j] = &As[0][0] + (w * 4 + j) * 512;
        lB[j] = &Bs[0][0] + (w * 4 + j) * 512;
    }
    int swz[2];
    swz[0] = ((0 + lg) ^ (l15 & 7)) * 8;
    swz[1] = ((4 + lg) ^ (l15 & 7)) * 8;
    const unsigned short* pA = &As[wm * 64 + l15][0];
    const unsigned short* pB = &Bs[wn * 64 + l15][0];

    for (int k0 = 0; k0 < K; k0 += 64) {
        __syncthreads();
        #pragma unroll
        for (int j = 0; j < 4; ++j) gload16(aptr[j] + k0, lA[j]);
        #pragma unroll
        for (int j = 0; j < 4; ++j) gload16(bptr[j] + k0, lB[j]);
        __syncthreads();

        #pragma unroll
        for (int ks = 0; ks < 2; ++ks) {
            short8 af[4], bf[4];
            #pragma unroll
            for (int mi = 0; mi < 4; ++mi)
                af[mi] = *(const short8*)(pA + mi * 16 * 64 + swz[ks]);
            #pragma unroll
            for (int ni = 0; ni < 4; ++ni)
                bf[ni] = *(const short8*)(pB + ni * 16 * 64 + swz[ks]);
            #pragma unroll
            for (int mi = 0; mi < 4; ++mi)
                #pragma unroll
                for (int ni = 0; ni < 4; ++ni)
                    acc[mi][ni] = __builtin_amdgcn_mfma_f32_16x16x32_bf16(af[mi], bf[ni], acc[mi][ni], 0, 0, 0);
        }
    }

    #pragma unroll
    for (int mi = 0; mi < 4; ++mi)
        #pragma unroll
        for (int ni = 0; ni < 4; ++ni)
            epi_store<EPI>(acc[mi][ni], m0 + wm * 64 + mi * 16 + lg * 4,
                           n0 + wn * 64 + ni * 16 + l15, N, bias, resid, outF, outH, outH2);
}

// ---------------- causal flash attention, swapped-operand softmax ----------------
__global__ __launch_bounds__(256) void attn_mfma(const unsigned short* __restrict__ qk,
                                                 const unsigned short* __restrict__ vT,
                                                 unsigned short* __restrict__ out) {
    int bid = blockIdx.x;
    int swz = (bid & 7) * 128 + (bid >> 3);
    int b  = swz >> 9;
    int h  = (swz >> 5) & 15;
    int qt = 31 - (swz & 31);
    int tid = threadIdx.x;
    int w = tid >> 6, l = tid & 63;
    int l15 = l & 15, lg = l >> 4;

    __shared__ __attribute__((aligned(16))) unsigned short Ks[64][72];
    __shared__ __attribute__((aligned(16))) unsigned short Vt[64][72];
    __shared__ __attribute__((aligned(16))) unsigned short Ps[4][16][72];

    int qrow = qt * 64 + w * 16 + l15;
    short8 qf[2];
    {
        const unsigned short* qp = qk + (size_t)(b * SEQ + qrow) * 2048 + h * DKV + lg * 8;
        qf[0] = *(const short8*)qp;
        qf[1] = *(const short8*)(qp + 32);
    }

    int srow = l >> 2;
    int scol = (l & 3) * 16;
    int krow = w * 16 + srow;
    const unsigned short* kbase = qk + (size_t)(b * SEQ + krow) * 2048 + 1024 + h * DKV + scol;
    const unsigned short* vbase = vT + ((size_t)(b * NHEAD + h) * DKV + krow) * SEQ + scol;

    short8 kr0 = *(const short8*)kbase;
    short8 kr1 = *(const short8*)(kbase + 8);
    short8 vr0 = *(const short8*)vbase;
    short8 vr1 = *(const short8*)(vbase + 8);

    float m = -1e30f, lsum = 0.0f;
    f32x4 oacc[4] = {};

    for (int kt = 0; kt <= qt; ++kt) {
        __syncthreads();
        *(short8*)&Ks[krow][scol]     = kr0;
        *(short8*)&Ks[krow][scol + 8] = kr1;
        *(short8*)&Vt[krow][scol]     = vr0;
        *(short8*)&Vt[krow][scol + 8] = vr1;
        __syncthreads();
        if (kt < qt) {
            const unsigned short* kp = kbase + (size_t)(kt + 1) * 64 * 2048;
            const unsigned short* vp = vbase + (kt + 1) * 64;
            kr0 = *(const short8*)kp;
            kr1 = *(const short8*)(kp + 8);
            vr0 = *(const short8*)vp;
            vr1 = *(const short8*)(vp + 8);
        }

        f32x4 sc[4] = {};
        __builtin_amdgcn_s_setprio(1);
        #pragma unroll
        for (int dstep = 0; dstep < 2; ++dstep) {
            #pragma unroll
            for (int st = 0; st < 4; ++st) {
                short8 kf = *(const short8*)&Ks[st * 16 + l15][dstep * 32 + lg * 8];
                sc[st] = __builtin_amdgcn_mfma_f32_16x16x32_bf16(kf, qf[dstep], sc[st], 0, 0, 0);
            }
        }
        __builtin_amdgcn_s_setprio(0);

        bool diag = (kt == qt);
        int klim = w * 16 + l15;
        float pv[4][4];
        float pmax = -1e30f;
        #pragma unroll
        for (int st = 0; st < 4; ++st) {
            #pragma unroll
            for (int j = 0; j < 4; ++j) {
                float s = sc[st][j] * 0.125f;
                if (diag && (st * 16 + lg * 4 + j > klim)) s = -1e30f;
                pv[st][j] = s;
                pmax = fmaxf(pmax, s);
            }
        }
        pmax = fmaxf(pmax, __shfl_xor(pmax, 16, 64));
        pmax = fmaxf(pmax, __shfl_xor(pmax, 32, 64));

        if (!__all(pmax - m <= 8.0f)) {
            float mn = fmaxf(m, pmax);
            float scl = __expf(m - mn);
            lsum *= scl;
            #pragma unroll
            for (int d = 0; d < 4; ++d)
                #pragma unroll
                for (int j = 0; j < 4; ++j)
                    oacc[d][j] *= scl;
            m = mn;
        }

        float ps = 0.0f;
        #pragma unroll
        for (int st = 0; st < 4; ++st) {
            ushort4 u;
            #pragma unroll
            for (int j = 0; j < 4; ++j) {
                float p = __expf(pv[st][j] - m);
                ps += p;
                ((unsigned short*)&u)[j] = f32_bf16(p);
            }
            *(ushort4*)&Ps[w][l15][st * 16 + lg * 4] = u;
        }
        ps += __shfl_xor(ps, 16, 64);
        ps += __shfl_xor(ps, 32, 64);
        lsum += ps;

        __builtin_amdgcn_s_setprio(1);
        #pragma unroll
        for (int ks = 0; ks < 2; ++ks) {
            short8 pf = *(const short8*)&Ps[w][l15][ks * 32 + lg * 8];
            #pragma unroll
            for (int d = 0; d < 4; ++d) {
                short8 vf = *(const short8*)&Vt[d * 16 + l15][ks * 32 + lg * 8];
                oacc[d] = __builtin_amdgcn_mfma_f32_16x16x32_bf16(vf, pf, oacc[d], 0, 0, 0);
            }
        }
        __builtin_amdgcn_s_setprio(0);
    }

    float inv = 1.0f / lsum;
    size_t ob = (size_t)(b * SEQ + qrow) * H_DIM + h * DKV;
    #pragma unroll
    for (int d = 0; d < 4; ++d) {
        ushort4 u;
        #pragma unroll
        for (int j = 0; j < 4; ++j)
            ((unsigned short*)&u)[j] = f32_bf16(oacc[d][j] * inv);
        *(ushort4*)&out[ob + d * 16 + lg * 4] = u;
    }
}

// ---------------- launch ----------------
extern "C" void kernel_launch(void* const* d_in, const int* in_sizes, int n_in,
                              void* d_out, int out_size, void* d_ws, size_t ws_size,
                              hipStream_t stream) {
    const float* x     = (const float*)d_in[0];
    const float* ln1w  = (const float*)d_in[1];
    const float* ln1b  = (const float*)d_in[2];
    const float* Wqkv  = (const float*)d_in[3];
    const float* bqkv  = (const float*)d_in[4];
    const float* Wo    = (const float*)d_in[5];
    const float* bo    = (const float*)d_in[6];
    const float* ln2w  = (const float*)d_in[7];
    const float* ln2b  = (const float*)d_in[8];
    const float* Wfc   = (const float*)d_in[9];
    const float* bfc   = (const float*)d_in[10];
    const float* Wproj = (const float*)d_in[11];
    const float* bproj = (const float*)d_in[12];
    float* out = (float*)d_out;

    char* ws = (char*)d_ws;
    size_t off = 0;
    auto take = [&](size_t bytes) {
        void* p = ws + off;
        off += (bytes + 255) & ~(size_t)255;
        return p;
    };

    unsigned short* WqT  = (unsigned short*)take((size_t)3072 * 1024 * 2);
    unsigned short* WoT  = (unsigned short*)take((size_t)1024 * 1024 * 2);
    unsigned short* WfcT = (unsigned short*)take((size_t)4096 * 1024 * 2);
    unsigned short* WpT  = (unsigned short*)take((size_t)1024 * 4096 * 2);
    unsigned short* xn1   = (unsigned short*)take((size_t)ROWS * 1024 * 2);
    unsigned short* qk_h  = (unsigned short*)take((size_t)ROWS * 2048 * 2);
    unsigned short* vT    = (unsigned short*)take((size_t)ROWS * 1024 * 2);
    unsigned short* attn  = (unsigned short*)take((size_t)ROWS * 1024 * 2);
    float*          x1    = (float*)take((size_t)ROWS * 1024 * 4);
    unsigned short* xn2   = (unsigned short*)take((size_t)ROWS * 1024 * 2);
    unsigned short* hbuf  = (unsigned short*)take((size_t)ROWS * 4096 * 2);

    // weight transposes fp32[K][N] -> bf16[N][K]
    transpose_bf16<<<dim3(3072 / 32, 1024 / 32), 256, 0, stream>>>(Wqkv,  WqT,  1024, 3072);
    transpose_bf16<<<dim3(1024 / 32, 1024 / 32), 256, 0, stream>>>(Wo,    WoT,  1024, 1024);
    transpose_bf16<<<dim3(4096 / 32, 1024 / 32), 256, 0, stream>>>(Wfc,   WfcT, 1024, 4096);
    transpose_bf16<<<dim3(1024 / 32, 4096 / 32), 256, 0, stream>>>(Wproj, WpT,  4096, 1024);

    // LN1 -> xn1 (bf16)
    ln_bf16<<<ROWS, 256, 0, stream>>>(x, ln1w, ln1b, xn1);

    // QKV: Q|K -> qk_h packed, V -> vT transposed   (grid 24x32 = 768)
    gemm128<4><<<768, 256, 0, stream>>>(xn1, WqT, bqkv, nullptr, nullptr, qk_h, vT, 24, 3072, 1024);

    // causal attention -> attn (bf16)
    attn_mfma<<<1024, 256, 0, stream>>>(qk_h, vT, attn);

    // x1 = x + attn @ Wo + bo   (grid 8x32 = 256)
    gemm128<1><<<256, 256, 0, stream>>>(attn, WoT, bo, x, x1, nullptr, nullptr, 8, 1024, 1024);

    // LN2 -> xn2 (bf16)
    ln_bf16<<<ROWS, 256, 0, stream>>>(x1, ln2w, ln2b, xn2);

    // h = gelu(xn2 @ Wfc + bfc)   (grid 32x32 = 1024)
    gemm128<2><<<1024, 256, 0, stream>>>(xn2, WfcT, bfc, nullptr, nullptr, hbuf, nullptr, 32, 4096, 1024);

    // out = x1 + h @ Wproj + bproj   (grid 8x32 = 256)
    gemm128<1><<<256, 256, 0, stream>>>(hbuf, WpT, bproj, x1, out, nullptr, nullptr, 8, 1024, 4096);
}